// Round 5
// baseline (397.332 us; speedup 1.0000x reference)
//
#include <hip/hip_runtime.h>
#include <math.h>

#define H 1024
#define N 512
#define M 128
#define EPSV 1e-8f

typedef float f32x4 __attribute__((ext_vector_type(4)));

__device__ __forceinline__ float wave_reduce_sum(float v) {
#pragma unroll
    for (int off = 32; off > 0; off >>= 1)
        v += __shfl_xor(v, off, 64);
    return v;
}

// ---------------------------------------------------------------------------
// Kernel A: small projections. 258 wave-tasks:
//   task 0..127   -> k[task]   = dot(Wk[task], x)   + bk[task]
//   task 128..255 -> a[t-128]  = dot(Wa[t-128], x)  + ba[t-128]
//   task 256      -> beta      = softplus(dot(Wbeta, x) + bbeta)
//   task 257      -> g         = sigmoid(dot(Wg, x) + bg)
// ws layout (floats): [0..127]=k  [128..255]=a  [256]=beta  [257]=g
// ---------------------------------------------------------------------------
__global__ void __launch_bounds__(256)
proj_kernel(const float* __restrict__ x,
            const float* __restrict__ Wk, const float* __restrict__ bk,
            const float* __restrict__ Wa, const float* __restrict__ ba,
            const float* __restrict__ Wbeta, const float* __restrict__ bbeta,
            const float* __restrict__ Wg, const float* __restrict__ bg,
            float* __restrict__ ws) {
    const int lane = threadIdx.x & 63;
    const int wid  = threadIdx.x >> 6;
    const int task = blockIdx.x * 4 + wid;
    if (task >= 258) return;

    const float* wrow;
    float bias;
    if (task < 128)      { wrow = Wk + task * H;         bias = bk[task]; }
    else if (task < 256) { wrow = Wa + (task - 128) * H; bias = ba[task - 128]; }
    else if (task == 256){ wrow = Wbeta;                 bias = bbeta[0]; }
    else                 { wrow = Wg;                    bias = bg[0]; }

    const f32x4* wv4 = reinterpret_cast<const f32x4*>(wrow);
    const f32x4* xv4 = reinterpret_cast<const f32x4*>(x);

    float acc = 0.f;
#pragma unroll
    for (int it = 0; it < 4; ++it) {
        const int idx = it * 64 + lane;                 // float4 index in row
        const f32x4 wv = __builtin_nontemporal_load(wv4 + idx);
        const f32x4 xv = xv4[idx];
        acc = fmaf(wv.x, xv.x, acc);
        acc = fmaf(wv.y, xv.y, acc);
        acc = fmaf(wv.z, xv.z, acc);
        acc = fmaf(wv.w, xv.w, acc);
    }
    acc = wave_reduce_sum(acc);
    if (lane == 0) {
        const float z = acc + bias;
        float outv;
        if (task < 256)       outv = z;                                        // k, a
        else if (task == 256) outv = fmaxf(z, 0.f) + log1pf(expf(-fabsf(z)));  // softplus
        else                  outv = 1.f / (1.f + expf(-z));                   // sigmoid
        ws[task] = outv;
    }
}

// ---------------------------------------------------------------------------
// Kernel B: addressing. Single block, 1024 threads (16 waves).
//   kn, cos[n] (one wave per mem row), softmax, state, read = state @ mem.
//   out[0..127] = read, out[128..639] = state.
// ---------------------------------------------------------------------------
__global__ void __launch_bounds__(1024)
addr_kernel(const float* __restrict__ mem, const float* __restrict__ prev,
            const float* __restrict__ ws, float* __restrict__ out) {
    __shared__ float sk[M];
    __shared__ float swc[N];
    __shared__ float sst[N];
    __shared__ float spart[8][M];
    __shared__ float sred[16];
    __shared__ float s_kn, s_mx, s_sum;

    const int tid  = threadIdx.x;
    const int lane = tid & 63;
    const int wid  = tid >> 6;

    // --- kn = max(||k||, eps); stage k in LDS
    float pk = 0.f;
    if (tid < M) { const float kv = ws[tid]; sk[tid] = kv; pk = kv * kv; }
    float r = wave_reduce_sum(pk);
    if (lane == 0) sred[wid] = r;
    __syncthreads();
    if (tid == 0) {
        float s = 0.f;
        for (int i = 0; i < 16; ++i) s += sred[i];
        s_kn = fmaxf(sqrtf(s), EPSV);
    }
    __syncthreads();
    const float beta = ws[256];
    const float g    = ws[257];
    const float kn   = s_kn;

    // --- beta * cos[n], one wave per row (each lane: 2 elements of M=128)
    for (int n = wid; n < N; n += 16) {
        const float* row = mem + n * M;
        const float a0 = row[lane], a1 = row[lane + 64];
        float d = fmaf(a0, sk[lane], a1 * sk[lane + 64]);
        float q = fmaf(a0, a0, a1 * a1);
#pragma unroll
        for (int off = 32; off > 0; off >>= 1) {
            d += __shfl_xor(d, off, 64);
            q += __shfl_xor(q, off, 64);
        }
        if (lane == 0) {
            const float mn = fmaxf(sqrtf(q), EPSV);
            swc[n] = beta * (d / (mn * kn));
        }
    }
    __syncthreads();

    // --- softmax over N=512 + gated interpolation
    const float v = (tid < N) ? swc[tid] : -INFINITY;
    float mx = v;
#pragma unroll
    for (int off = 32; off > 0; off >>= 1) mx = fmaxf(mx, __shfl_xor(mx, off, 64));
    if (lane == 0) sred[wid] = mx;
    __syncthreads();
    if (tid == 0) {
        float m2 = -INFINITY;
        for (int i = 0; i < 16; ++i) m2 = fmaxf(m2, sred[i]);
        s_mx = m2;
    }
    __syncthreads();
    const float ex = (tid < N) ? expf(v - s_mx) : 0.f;
    float se = wave_reduce_sum(ex);
    if (lane == 0) sred[wid] = se;
    __syncthreads();
    if (tid == 0) {
        float s = 0.f;
        for (int i = 0; i < 16; ++i) s += sred[i];
        s_sum = s;
    }
    __syncthreads();
    if (tid < N) {
        const float st = g * (ex / s_sum) + (1.f - g) * prev[tid];
        sst[tid] = st;
        out[M + tid] = st;          // state output
    }
    __syncthreads();

    // --- read = state @ mem; column t, 8-way split over n, coalesced loads
    const int t = tid & 127, j = tid >> 7;
    float p = 0.f;
    const int n0 = j * 64;
    for (int n = n0; n < n0 + 64; ++n)
        p = fmaf(sst[n], mem[n * M + t], p);
    spart[j][t] = p;
    __syncthreads();
    if (tid < M) {
        float s = 0.f;
#pragma unroll
        for (int jj = 0; jj < 8; ++jj) s += spart[jj][tid];
        out[tid] = s;               // read output
    }
}

// ---------------------------------------------------------------------------
// Kernel C: the 256 MiB matvec + fused memory write.
//   One wave per We row r (r = n*M + m):
//     E = sigmoid(dot(We[r], x) + be[r])
//     new_mem[r] = mem[r] * (1 - state[n]*E) + state[n]*a[m]
//   We is streamed exactly once -> non-temporal loads (keeps mem in L2/L3).
// ---------------------------------------------------------------------------
__global__ void __launch_bounds__(256)
write_kernel(const float* __restrict__ x, const float* __restrict__ We,
             const float* __restrict__ be, const float* __restrict__ mem,
             const float* __restrict__ ws, const float* __restrict__ state,
             float* __restrict__ nm) {
    __shared__ float xs[H];
    const int tid = threadIdx.x;
    // stage x (4 KB) in LDS: 256 threads x float4, coalesced
    reinterpret_cast<f32x4*>(xs)[tid] = reinterpret_cast<const f32x4*>(x)[tid];
    __syncthreads();

    const int lane = tid & 63;
    const int wid  = tid >> 6;
    const int r    = blockIdx.x * 4 + wid;          // 0..65535
    const f32x4* wrow = reinterpret_cast<const f32x4*>(We + (size_t)r * H);
    const f32x4* xls  = reinterpret_cast<const f32x4*>(xs);

    float acc = 0.f;
#pragma unroll
    for (int it = 0; it < 4; ++it) {
        const int idx = it * 64 + lane;             // float4 index within row
        const f32x4 wv = __builtin_nontemporal_load(wrow + idx);
        const f32x4 xv = xls[idx];
        acc = fmaf(wv.x, xv.x, acc);
        acc = fmaf(wv.y, xv.y, acc);
        acc = fmaf(wv.z, xv.z, acc);
        acc = fmaf(wv.w, xv.w, acc);
    }
    acc = wave_reduce_sum(acc);
    if (lane == 0) {
        const int n = r >> 7, m = r & 127;
        const float E  = 1.f / (1.f + expf(-(acc + be[r])));
        const float st = state[n];
        const float av = ws[128 + m];
        __builtin_nontemporal_store(
            mem[r] * (1.f - st * E) + st * av, nm + r);
    }
}

// ---------------------------------------------------------------------------
extern "C" void kernel_launch(void* const* d_in, const int* in_sizes, int n_in,
                              void* d_out, int out_size, void* d_ws, size_t ws_size,
                              hipStream_t stream) {
    const float* x     = (const float*)d_in[0];
    const float* prev  = (const float*)d_in[1];
    const float* mem   = (const float*)d_in[2];
    const float* Wk    = (const float*)d_in[3];
    const float* bk    = (const float*)d_in[4];
    const float* Wbeta = (const float*)d_in[5];
    const float* bbeta = (const float*)d_in[6];
    const float* Wg    = (const float*)d_in[7];
    const float* bg    = (const float*)d_in[8];
    // d_in[9]=Ws, d_in[10]=bs, d_in[11]=Wgamma, d_in[12]=bgamma : dead outputs, skipped
    const float* We    = (const float*)d_in[13];
    const float* be    = (const float*)d_in[14];
    const float* Wa    = (const float*)d_in[15];
    const float* ba    = (const float*)d_in[16];

    float* out = (float*)d_out;           // [0..127]=read [128..639]=state [640..66175]=new_memory
    float* ws  = (float*)d_ws;            // [0..127]=k [128..255]=a [256]=beta [257]=g

    proj_kernel<<<65, 256, 0, stream>>>(x, Wk, bk, Wa, ba, Wbeta, bbeta, Wg, bg, ws);
    addr_kernel<<<1, 1024, 0, stream>>>(mem, prev, ws, out);
    write_kernel<<<16384, 256, 0, stream>>>(x, We, be, mem, ws, out + M, out + M + N);
}